// Round 4
// baseline (301.513 us; speedup 1.0000x reference)
//
#include <hip/hip_runtime.h>
#include <math.h>

#define N     12
#define HID   64
#define SLOPE 0.2f
#define ALPHA 0.1f

typedef float v2f __attribute__((ext_vector_type(2)));
typedef float v4f __attribute__((ext_vector_type(4)));

// flat output offsets (float32 elements)
#define OUT0 0          // batch[:,:,:4]
#define OUT1 196608     // batch[:,:,4:5]
#define OUT2 245760     // logits
#define OUT3 442368     // values
#define OUT4 491520     // latent

// ws layout: 7 transposed 64x64 matrices (wsT[m*4096 + t*64 + c] = W[c*64+t]),
// then labT[c*64+h] = lab_w[h*4+c] (256 floats)
__global__ void prep_kernel(const float* __restrict__ enc_w2,
                            const float* __restrict__ g2_wl, const float* __restrict__ g2_wr,
                            const float* __restrict__ g3_wl, const float* __restrict__ g3_wr,
                            const float* __restrict__ g4_wl, const float* __restrict__ g4_wr,
                            const float* __restrict__ lab_w,
                            float* __restrict__ ws) {
    int t = threadIdx.x;
    if (blockIdx.x == 448) {
        #pragma unroll
        for (int c = 0; c < 4; c++) ws[7*4096 + c*64 + t] = lab_w[t*4 + c];
        return;
    }
    int m = blockIdx.x >> 6, c = blockIdx.x & 63;
    const float* src;
    switch (m) {
        case 0: src = enc_w2; break;
        case 1: src = g2_wl;  break;
        case 2: src = g2_wr;  break;
        case 3: src = g3_wl;  break;
        case 4: src = g3_wr;  break;
        case 5: src = g4_wl;  break;
        default: src = g4_wr; break;
    }
    ws[m*4096 + t*64 + c] = src[c*64 + t];
}

// LDS budget: 3 * 12*64 floats + 144-float pool = 9792 B -> 16 blocks/CU.
// launch_bounds(64,3): (64,4) in R3 squeezed VGPRs to 64 and SPILLED
// (FETCH/WRITE 153/139 MB of scratch traffic). (64,3) gave 80 VGPR spill-free
// in R2; 80 <= 128 so the HW still allows 16 waves/CU -> LDS is the limiter.
template<bool TW>
__global__ __launch_bounds__(64, 3) void gae_kernel(
    const float* __restrict__ batch,
    const float* __restrict__ enc_w1, const float* __restrict__ enc_b1,
    const float* __restrict__ enc_w2, const float* __restrict__ enc_b2,
    const float* __restrict__ enc_w3, const float* __restrict__ enc_b3,
    const float* __restrict__ g1_wl, const float* __restrict__ g1_wr,
    const float* __restrict__ g1_att, const float* __restrict__ g1_b,
    const float* __restrict__ g2_wl, const float* __restrict__ g2_wr,
    const float* __restrict__ g2_att, const float* __restrict__ g2_b,
    const float* __restrict__ g3_wl, const float* __restrict__ g3_wr,
    const float* __restrict__ g3_att, const float* __restrict__ g3_b,
    const float* __restrict__ g4_wl, const float* __restrict__ g4_wr,
    const float* __restrict__ g4_att, const float* __restrict__ g4_b,
    const float* __restrict__ lab_w, const float* __restrict__ lab_b,
    const float* __restrict__ val_w, const float* __restrict__ val_b,
    const float* __restrict__ skip_w, const float* __restrict__ skip_b,
    const float* __restrict__ wsT,
    float* __restrict__ out)
{
    const int b = blockIdx.x;
    const int t = threadIdx.x;

    __shared__ __align__(16) float lds[3*N*HID + 144];
    float* bufL = lds;
    float* bufR = lds + N*HID;
    float* xB   = lds + 2*N*HID;
    float* pool = lds + 3*N*HID;   // batch(60) -> lat(36) -> e(144), sequential reuse

    const v2f z2 = {0.f, 0.f};
    const v4f z4 = {0.f, 0.f, 0.f, 0.f};
    const v4f s4 = {SLOPE, SLOPE, SLOPE, SLOPE};

    // score-pair decomposition (144 pairs over 64 lanes, 3 slots)
    const int p0 = t,        i0 = p0 / N, j0 = p0 - i0*N;
    const int p1 = t + 64,   i1 = p1 / N, j1 = p1 - i1*N;
    const int p2 = (t < 16) ? (t + 128) : 143;
    const int i2 = p2 / N,   j2 = p2 - i2*N;

    // ---- stage batch into pool, emit passthrough outputs 0/1 ----
    if (t < N*5) {
        float v = batch[b*(N*5) + t];
        pool[t] = v;
        int i = t / 5, f = t - i*5;
        if (f < 4) out[OUT0 + (size_t)b*(N*4) + i*4 + f] = v;
        else       out[OUT1 + (size_t)b*N + i] = v;
    }
    __syncthreads();

    // ---- encoder layer 1 ----
    {
        float acc[N];
        float bias = enc_b1[t];
        #pragma unroll
        for (int i=0;i<N;i++) acc[i] = bias;
        #pragma unroll
        for (int f=0; f<5; f++) {
            float w = enc_w1[f*HID + t];
            #pragma unroll
            for (int i=0;i<N;i++) acc[i] = fmaf(pool[i*5+f], w, acc[i]);
        }
        #pragma unroll
        for (int i=0;i<N;i++) bufL[i*HID + ((t + 4*i)&63)] = fmaxf(acc[i], 0.f);
    }
    __syncthreads();

    // ---- encoder layer 2 (packed fp32) ----
    {
        v2f acc[N];
        #pragma unroll
        for (int i=0;i<N;i++) acc[i] = z2;
        const float* w2p = TW ? (wsT + 0*4096 + t*HID) : nullptr;
        #pragma unroll
        for (int c=0;c<HID;c+=4) {
            v2f w01, w23;
            if (TW) {
                v4f w4 = *reinterpret_cast<const v4f*>(&w2p[c]);
                w01 = w4.xy; w23 = w4.zw;
            } else {
                w01 = (v2f){enc_w2[(c+0)*HID+t], enc_w2[(c+1)*HID+t]};
                w23 = (v2f){enc_w2[(c+2)*HID+t], enc_w2[(c+3)*HID+t]};
            }
            #pragma unroll
            for (int i=0;i<N;i++) {
                v4f xv = *reinterpret_cast<const v4f*>(&bufL[i*HID + ((c + 4*i)&63)]);
                acc[i] = __builtin_elementwise_fma(xv.xy, w01, acc[i]);
                acc[i] = __builtin_elementwise_fma(xv.zw, w23, acc[i]);
            }
        }
        float bias = enc_b2[t];
        #pragma unroll
        for (int i=0;i<N;i++) bufR[i*HID + ((t + 4*i)&63)] = fmaxf(bias + acc[i].x + acc[i].y, 0.f);
    }
    __syncthreads();

    // ---- latent = h2 @ W3 + b3 (lanes 0..35) -> pool[0..35] ----
    if (t < N*3) {
        int i = t / 3, c = t - i*3;
        float acc = enc_b3[c];
        #pragma unroll
        for (int k=0;k<HID;k+=4) {
            v4f xv = *reinterpret_cast<const v4f*>(&bufR[i*HID + ((k + 4*i)&63)]);
            acc = fmaf(xv.x, enc_w3[(k+0)*3+c], acc);
            acc = fmaf(xv.y, enc_w3[(k+1)*3+c], acc);
            acc = fmaf(xv.z, enc_w3[(k+2)*3+c], acc);
            acc = fmaf(xv.w, enc_w3[(k+3)*3+c], acc);
        }
        pool[t] = acc;
        out[OUT4 + (size_t)b*(N*3) + t] = acc;
    }
    __syncthreads();

    // ---- skip connection -> registers ----
    float skipv[N];
    {
        float w0 = skip_w[t], w1 = skip_w[HID+t], w2 = skip_w[2*HID+t];
        float bias = skip_b[t];
        #pragma unroll
        for (int i=0;i<N;i++) {
            float v = bias;
            v = fmaf(pool[i*3+0], w0, v);
            v = fmaf(pool[i*3+1], w1, v);
            v = fmaf(pool[i*3+2], w2, v);
            skipv[i] = v;
        }
    }

    // ---- Gabriel adjacency via ballots (no LDS matrix) ----
    auto gab = [&](int i, int j)->bool {
        if (i == j) return false;
        float pix = pool[i*3], piy = pool[i*3+1];
        float pjx = pool[j*3], pjy = pool[j*3+1];
        float mx = (pix + pjx) * 0.5f, my = (piy + pjy) * 0.5f;
        float dx = pix - pjx, dy = piy - pjy;
        float r2 = (dx*dx + dy*dy) * 0.25f;
        bool g = true;
        #pragma unroll
        for (int k=0;k<N;k++) {
            float ex = pool[k*3] - mx, ey = pool[k*3+1] - my;
            bool ok = (k == i) || (k == j) || (ex*ex + ey*ey > r2);
            g = g && ok;
        }
        return g;
    };
    unsigned long long gb0 = __ballot(gab(i0, j0));
    unsigned long long gb1 = __ballot(gab(i1, j1));
    unsigned long long gb2 = __ballot((t < 16) && gab(i2, j2));
    auto gbit = [&](int p)->int {
        unsigned long long m = (p < 64) ? gb0 : ((p < 128) ? gb1 : gb2);
        return (int)((m >> (p & 63)) & 1ull);
    };
    const int adjA = gbit(p0) | gbit(j0*N+i0) | (i0 == j0);
    const int adjB = gbit(p1) | gbit(j1*N+i1) | (i1 == j1);
    const int adjC = gbit(p2) | gbit(j2*N+i2) | (i2 == j2);

    // ---- GATv2 core: score -> softmax -> aggregate ----
    auto gat_core = [&](const float* __restrict__ att, const float* __restrict__ gb,
                        float* __restrict__ xout, int rotOut, int useSkip) {
        __syncthreads();   // staged xl/xr visible
        {
            v4f aA = z4, aB = z4, aC = z4;
            #pragma unroll
            for (int h=0; h<HID; h+=4) {
                v4f a4 = *reinterpret_cast<const v4f*>(&att[h]);   // uniform -> scalar load
                {
                    v4f xl = *reinterpret_cast<const v4f*>(&bufL[j0*HID + ((h + 4*j0)&63)]);
                    v4f xr = *reinterpret_cast<const v4f*>(&bufR[i0*HID + ((h + 4*i0)&63)]);
                    v4f s = xl + xr;
                    v4f l = __builtin_elementwise_fma(s4, __builtin_elementwise_min(s, z4),
                                                     __builtin_elementwise_max(s, z4));
                    aA = __builtin_elementwise_fma(a4, l, aA);
                }
                {
                    v4f xl = *reinterpret_cast<const v4f*>(&bufL[j1*HID + ((h + 4*j1)&63)]);
                    v4f xr = *reinterpret_cast<const v4f*>(&bufR[i1*HID + ((h + 4*i1)&63)]);
                    v4f s = xl + xr;
                    v4f l = __builtin_elementwise_fma(s4, __builtin_elementwise_min(s, z4),
                                                     __builtin_elementwise_max(s, z4));
                    aB = __builtin_elementwise_fma(a4, l, aB);
                }
                {
                    v4f xl = *reinterpret_cast<const v4f*>(&bufL[j2*HID + ((h + 4*j2)&63)]);
                    v4f xr = *reinterpret_cast<const v4f*>(&bufR[i2*HID + ((h + 4*i2)&63)]);
                    v4f s = xl + xr;
                    v4f l = __builtin_elementwise_fma(s4, __builtin_elementwise_min(s, z4),
                                                     __builtin_elementwise_max(s, z4));
                    aC = __builtin_elementwise_fma(a4, l, aC);
                }
            }
            float e0 = (aA.x + aA.y) + (aA.z + aA.w);
            float e1 = (aB.x + aB.y) + (aB.z + aB.w);
            float e2 = (aC.x + aC.y) + (aC.z + aC.w);
            pool[p0] = adjA ? e0 : -1e9f;
            pool[p1] = adjB ? e1 : -1e9f;
            if (t < 16) pool[p2] = adjC ? e2 : -1e9f;
        }
        __syncthreads();
        if (t < N) {   // row softmax
            float m = -2e9f;
            #pragma unroll
            for (int j=0;j<N;j++) m = fmaxf(m, pool[t*N+j]);
            float tmp[N]; float sum = 0.f;
            #pragma unroll
            for (int j=0;j<N;j++) { float v = __expf(pool[t*N+j] - m); tmp[j] = v; sum += v; }
            float inv = 1.0f / sum;
            #pragma unroll
            for (int j=0;j<N;j++) pool[t*N+j] = tmp[j] * inv;
        }
        __syncthreads();
        {
            float xj[N];
            #pragma unroll
            for (int j=0;j<N;j++) xj[j] = bufL[j*HID + ((t + 4*j)&63)];
            v4f X0 = {xj[0], xj[1], xj[2],  xj[3]};
            v4f X1 = {xj[4], xj[5], xj[6],  xj[7]};
            v4f X2 = {xj[8], xj[9], xj[10], xj[11]};
            float bias = gb[t];
            #pragma unroll
            for (int i=0;i<N;i++) {
                const v4f* ep = reinterpret_cast<const v4f*>(&pool[i*N]);
                v4f acc = __builtin_elementwise_fma(ep[0], X0,
                          __builtin_elementwise_fma(ep[1], X1, ep[2]*X2));
                float r = bias + ((acc.x + acc.y) + (acc.z + acc.w));
                if (useSkip) r = fmaf(ALPHA, skipv[i], r);
                xout[i*HID + ((t + rotOut*i)&63)] = fmaxf(r, 0.f);
            }
        }
        __syncthreads();
    };

    // ---- stage xl/xr (packed fp32) ----
    auto stage = [&](const float* __restrict__ xin, int rotIn,
                     const float* __restrict__ wlT, const float* __restrict__ wrT,
                     const float* __restrict__ wl, const float* __restrict__ wr) {
        v2f al[N], ar[N];
        #pragma unroll
        for (int i=0;i<N;i++) { al[i] = z2; ar[i] = z2; }
        #pragma unroll
        for (int c=0;c<HID;c+=4) {
            v2f wl01, wl23, wr01, wr23;
            if (TW) {
                v4f w4 = *reinterpret_cast<const v4f*>(&wlT[c]);
                v4f u4 = *reinterpret_cast<const v4f*>(&wrT[c]);
                wl01 = w4.xy; wl23 = w4.zw;
                wr01 = u4.xy; wr23 = u4.zw;
            } else {
                wl01 = (v2f){wl[(c+0)*HID+t], wl[(c+1)*HID+t]};
                wl23 = (v2f){wl[(c+2)*HID+t], wl[(c+3)*HID+t]};
                wr01 = (v2f){wr[(c+0)*HID+t], wr[(c+1)*HID+t]};
                wr23 = (v2f){wr[(c+2)*HID+t], wr[(c+3)*HID+t]};
            }
            #pragma unroll
            for (int i=0;i<N;i++) {
                v4f xv = *reinterpret_cast<const v4f*>(&xin[i*HID + ((c + rotIn*i)&63)]);
                al[i] = __builtin_elementwise_fma(xv.xy, wl01, al[i]);
                al[i] = __builtin_elementwise_fma(xv.zw, wl23, al[i]);
                ar[i] = __builtin_elementwise_fma(xv.xy, wr01, ar[i]);
                ar[i] = __builtin_elementwise_fma(xv.zw, wr23, ar[i]);
            }
        }
        #pragma unroll
        for (int i=0;i<N;i++) {
            bufL[i*HID + ((t + 4*i)&63)] = al[i].x + al[i].y;
            bufR[i*HID + ((t + 4*i)&63)] = ar[i].x + ar[i].y;
        }
    };

    // ---- GAT layer 1 (cin = 1; x0 = lat[:,2] from pool) ----
    {
        float wlv = g1_wl[t], wrv = g1_wr[t];
        #pragma unroll
        for (int i=0;i<N;i++) {
            float v = pool[i*3+2];
            bufL[i*HID + ((t + 4*i)&63)] = v * wlv;
            bufR[i*HID + ((t + 4*i)&63)] = v * wrv;
        }
    }
    gat_core(g1_att, g1_b, bufR, 4, 0);     // x1 -> bufR (rotated)

    // ---- GAT layer 2 ----
    stage(bufR, 4, TW ? wsT + 1*4096 + t*HID : nullptr,
                   TW ? wsT + 2*4096 + t*HID : nullptr, g2_wl, g2_wr);
    gat_core(g2_att, g2_b, xB, 0, 0);       // x2 -> xB (plain; persists)

    // ---- GAT layer 3 ----
    stage(xB, 0, TW ? wsT + 3*4096 + t*HID : nullptr,
                 TW ? wsT + 4*4096 + t*HID : nullptr, g3_wl, g3_wr);
    gat_core(g3_att, g3_b, bufR, 4, 1);     // x3 -> bufR

    // ---- logits head: x3 @ lab_w + lab_b ----
    if (t < N*4) {
        int i = t >> 2, c = t & 3;
        float acc = lab_b[c];
        if (TW) {
            const float* lwT = wsT + 7*4096 + c*HID;
            #pragma unroll
            for (int h=0;h<HID;h+=4) {
                v4f xv = *reinterpret_cast<const v4f*>(&bufR[i*HID + ((h + 4*i)&63)]);
                v4f w4 = *reinterpret_cast<const v4f*>(&lwT[h]);
                acc = fmaf(xv.x, w4.x, acc);
                acc = fmaf(xv.y, w4.y, acc);
                acc = fmaf(xv.z, w4.z, acc);
                acc = fmaf(xv.w, w4.w, acc);
            }
        } else {
            #pragma unroll
            for (int h=0;h<HID;h+=4) {
                v4f xv = *reinterpret_cast<const v4f*>(&bufR[i*HID + ((h + 4*i)&63)]);
                acc = fmaf(xv.x, lab_w[(h+0)*4+c], acc);
                acc = fmaf(xv.y, lab_w[(h+1)*4+c], acc);
                acc = fmaf(xv.z, lab_w[(h+2)*4+c], acc);
                acc = fmaf(xv.w, lab_w[(h+3)*4+c], acc);
            }
        }
        out[OUT2 + (size_t)b*(N*4) + t] = acc;
    }

    // ---- GAT layer 4 ----
    stage(xB, 0, TW ? wsT + 5*4096 + t*HID : nullptr,
                 TW ? wsT + 6*4096 + t*HID : nullptr, g4_wl, g4_wr);
    gat_core(g4_att, g4_b, bufR, 4, 1);     // x4 -> bufR

    // ---- values head ----
    if (t < N) {
        float acc = val_b[0];
        #pragma unroll
        for (int h=0;h<HID;h+=4) {
            v4f xv = *reinterpret_cast<const v4f*>(&bufR[t*HID + ((h + 4*t)&63)]);
            v4f w4 = *reinterpret_cast<const v4f*>(&val_w[h]);
            acc = fmaf(xv.x, w4.x, acc);
            acc = fmaf(xv.y, w4.y, acc);
            acc = fmaf(xv.z, w4.z, acc);
            acc = fmaf(xv.w, w4.w, acc);
        }
        out[OUT3 + (size_t)b*N + t] = acc;
    }
}

extern "C" void kernel_launch(void* const* d_in, const int* in_sizes, int n_in,
                              void* d_out, int out_size, void* d_ws, size_t ws_size,
                              hipStream_t stream) {
    (void)in_sizes; (void)n_in; (void)out_size;
    const bool useT = (ws_size >= (7*4096 + 256)*sizeof(float));
    if (useT) {
        prep_kernel<<<dim3(449), dim3(64), 0, stream>>>(
            (const float*)d_in[3],
            (const float*)d_in[11], (const float*)d_in[12],
            (const float*)d_in[15], (const float*)d_in[16],
            (const float*)d_in[19], (const float*)d_in[20],
            (const float*)d_in[23],
            (float*)d_ws);
        gae_kernel<true><<<dim3(4096), dim3(64), 0, stream>>>(
            (const float*)d_in[0],
            (const float*)d_in[1],  (const float*)d_in[2],
            (const float*)d_in[3],  (const float*)d_in[4],
            (const float*)d_in[5],  (const float*)d_in[6],
            (const float*)d_in[7],  (const float*)d_in[8],  (const float*)d_in[9],  (const float*)d_in[10],
            (const float*)d_in[11], (const float*)d_in[12], (const float*)d_in[13], (const float*)d_in[14],
            (const float*)d_in[15], (const float*)d_in[16], (const float*)d_in[17], (const float*)d_in[18],
            (const float*)d_in[19], (const float*)d_in[20], (const float*)d_in[21], (const float*)d_in[22],
            (const float*)d_in[23], (const float*)d_in[24],
            (const float*)d_in[25], (const float*)d_in[26],
            (const float*)d_in[27], (const float*)d_in[28],
            (const float*)d_ws,
            (float*)d_out);
    } else {
        gae_kernel<false><<<dim3(4096), dim3(64), 0, stream>>>(
            (const float*)d_in[0],
            (const float*)d_in[1],  (const float*)d_in[2],
            (const float*)d_in[3],  (const float*)d_in[4],
            (const float*)d_in[5],  (const float*)d_in[6],
            (const float*)d_in[7],  (const float*)d_in[8],  (const float*)d_in[9],  (const float*)d_in[10],
            (const float*)d_in[11], (const float*)d_in[12], (const float*)d_in[13], (const float*)d_in[14],
            (const float*)d_in[15], (const float*)d_in[16], (const float*)d_in[17], (const float*)d_in[18],
            (const float*)d_in[19], (const float*)d_in[20], (const float*)d_in[21], (const float*)d_in[22],
            (const float*)d_in[23], (const float*)d_in[24],
            (const float*)d_in[25], (const float*)d_in[26],
            (const float*)d_in[27], (const float*)d_in[28],
            nullptr,
            (float*)d_out);
    }
}

// Round 5
// 223.663 us; speedup vs baseline: 1.3481x; 1.3481x over previous
//
#include <hip/hip_runtime.h>
#include <math.h>

#define N     12
#define HID   64
#define SLOPE 0.2f
#define ALPHA 0.1f

typedef float v2f __attribute__((ext_vector_type(2)));
typedef float v4f __attribute__((ext_vector_type(4)));

// flat output offsets (float32 elements)
#define OUT0 0          // batch[:,:,:4]
#define OUT1 196608     // batch[:,:,4:5]
#define OUT2 245760     // logits
#define OUT3 442368     // values
#define OUT4 491520     // latent

// ws layout: 7 transposed 64x64 matrices (wsT[m*4096 + t*64 + c] = W[c*64+t]),
// then labT[c*64+h] = lab_w[h*4+c] (256 floats)
__global__ void prep_kernel(const float* __restrict__ enc_w2,
                            const float* __restrict__ g2_wl, const float* __restrict__ g2_wr,
                            const float* __restrict__ g3_wl, const float* __restrict__ g3_wr,
                            const float* __restrict__ g4_wl, const float* __restrict__ g4_wr,
                            const float* __restrict__ lab_w,
                            float* __restrict__ ws) {
    int t = threadIdx.x;
    if (blockIdx.x == 448) {
        #pragma unroll
        for (int c = 0; c < 4; c++) ws[7*4096 + c*64 + t] = lab_w[t*4 + c];
        return;
    }
    int m = blockIdx.x >> 6, c = blockIdx.x & 63;
    const float* src;
    switch (m) {
        case 0: src = enc_w2; break;
        case 1: src = g2_wl;  break;
        case 2: src = g2_wr;  break;
        case 3: src = g3_wl;  break;
        case 4: src = g3_wr;  break;
        case 5: src = g4_wl;  break;
        default: src = g4_wr; break;
    }
    ws[m*4096 + t*64 + c] = src[c*64 + t];
}

// LDS budget: 3 * 12*64 floats + 144-float pool = 9792 B -> 16 blocks/CU.
// IMPORTANT (R3/R4 lesson): do NOT fully unroll the 16-iteration K-loops
// (enc2 / stage / score). Full unroll spilled the accumulator arrays to
// scratch (~100+ MB FETCH/WRITE of pure spill traffic, 2x regression).
// Rolled loops (R2 behavior) are spill-free at (64,3).
template<bool TW>
__global__ __launch_bounds__(64, 3) void gae_kernel(
    const float* __restrict__ batch,
    const float* __restrict__ enc_w1, const float* __restrict__ enc_b1,
    const float* __restrict__ enc_w2, const float* __restrict__ enc_b2,
    const float* __restrict__ enc_w3, const float* __restrict__ enc_b3,
    const float* __restrict__ g1_wl, const float* __restrict__ g1_wr,
    const float* __restrict__ g1_att, const float* __restrict__ g1_b,
    const float* __restrict__ g2_wl, const float* __restrict__ g2_wr,
    const float* __restrict__ g2_att, const float* __restrict__ g2_b,
    const float* __restrict__ g3_wl, const float* __restrict__ g3_wr,
    const float* __restrict__ g3_att, const float* __restrict__ g3_b,
    const float* __restrict__ g4_wl, const float* __restrict__ g4_wr,
    const float* __restrict__ g4_att, const float* __restrict__ g4_b,
    const float* __restrict__ lab_w, const float* __restrict__ lab_b,
    const float* __restrict__ val_w, const float* __restrict__ val_b,
    const float* __restrict__ skip_w, const float* __restrict__ skip_b,
    const float* __restrict__ wsT,
    float* __restrict__ out)
{
    const int b = blockIdx.x;
    const int t = threadIdx.x;

    __shared__ __align__(16) float lds[3*N*HID + 144];
    float* bufL = lds;
    float* bufR = lds + N*HID;
    float* xB   = lds + 2*N*HID;
    float* pool = lds + 3*N*HID;   // batch(60) -> lat(36) -> e(144), sequential reuse

    const v2f z2 = {0.f, 0.f};
    const v4f z4 = {0.f, 0.f, 0.f, 0.f};
    const v4f s4 = {SLOPE, SLOPE, SLOPE, SLOPE};

    // score-pair decomposition (144 pairs over 64 lanes, 3 slots)
    const int p0 = t,        i0 = p0 / N, j0 = p0 - i0*N;
    const int p1 = t + 64,   i1 = p1 / N, j1 = p1 - i1*N;
    const int p2 = (t < 16) ? (t + 128) : 143;
    const int i2 = p2 / N,   j2 = p2 - i2*N;

    // ---- stage batch into pool, emit passthrough outputs 0/1 ----
    if (t < N*5) {
        float v = batch[b*(N*5) + t];
        pool[t] = v;
        int i = t / 5, f = t - i*5;
        if (f < 4) out[OUT0 + (size_t)b*(N*4) + i*4 + f] = v;
        else       out[OUT1 + (size_t)b*N + i] = v;
    }
    __syncthreads();

    // ---- encoder layer 1 ----
    {
        float acc[N];
        float bias = enc_b1[t];
        #pragma unroll
        for (int i=0;i<N;i++) acc[i] = bias;
        #pragma unroll
        for (int f=0; f<5; f++) {
            float w = enc_w1[f*HID + t];
            #pragma unroll
            for (int i=0;i<N;i++) acc[i] = fmaf(pool[i*5+f], w, acc[i]);
        }
        #pragma unroll
        for (int i=0;i<N;i++) bufL[i*HID + ((t + 4*i)&63)] = fmaxf(acc[i], 0.f);
    }
    __syncthreads();

    // ---- encoder layer 2 (packed fp32; K-loop kept ROLLED) ----
    {
        v2f acc[N];
        #pragma unroll
        for (int i=0;i<N;i++) acc[i] = z2;
        const float* w2p = TW ? (wsT + 0*4096 + t*HID) : nullptr;
        for (int c=0;c<HID;c+=4) {
            v2f w01, w23;
            if (TW) {
                v4f w4 = *reinterpret_cast<const v4f*>(&w2p[c]);
                w01 = w4.xy; w23 = w4.zw;
            } else {
                w01 = (v2f){enc_w2[(c+0)*HID+t], enc_w2[(c+1)*HID+t]};
                w23 = (v2f){enc_w2[(c+2)*HID+t], enc_w2[(c+3)*HID+t]};
            }
            #pragma unroll
            for (int i=0;i<N;i++) {
                v4f xv = *reinterpret_cast<const v4f*>(&bufL[i*HID + ((c + 4*i)&63)]);
                acc[i] = __builtin_elementwise_fma(xv.xy, w01, acc[i]);
                acc[i] = __builtin_elementwise_fma(xv.zw, w23, acc[i]);
            }
        }
        float bias = enc_b2[t];
        #pragma unroll
        for (int i=0;i<N;i++) bufR[i*HID + ((t + 4*i)&63)] = fmaxf(bias + acc[i].x + acc[i].y, 0.f);
    }
    __syncthreads();

    // ---- latent = h2 @ W3 + b3 (lanes 0..35) -> pool[0..35] ----
    if (t < N*3) {
        int i = t / 3, c = t - i*3;
        float acc = enc_b3[c];
        for (int k=0;k<HID;k+=4) {
            v4f xv = *reinterpret_cast<const v4f*>(&bufR[i*HID + ((k + 4*i)&63)]);
            acc = fmaf(xv.x, enc_w3[(k+0)*3+c], acc);
            acc = fmaf(xv.y, enc_w3[(k+1)*3+c], acc);
            acc = fmaf(xv.z, enc_w3[(k+2)*3+c], acc);
            acc = fmaf(xv.w, enc_w3[(k+3)*3+c], acc);
        }
        pool[t] = acc;
        out[OUT4 + (size_t)b*(N*3) + t] = acc;
    }
    __syncthreads();

    // ---- skip connection -> registers ----
    float skipv[N];
    {
        float w0 = skip_w[t], w1 = skip_w[HID+t], w2 = skip_w[2*HID+t];
        float bias = skip_b[t];
        #pragma unroll
        for (int i=0;i<N;i++) {
            float v = bias;
            v = fmaf(pool[i*3+0], w0, v);
            v = fmaf(pool[i*3+1], w1, v);
            v = fmaf(pool[i*3+2], w2, v);
            skipv[i] = v;
        }
    }

    // ---- Gabriel adjacency via ballots (no LDS matrix) ----
    auto gab = [&](int i, int j)->bool {
        if (i == j) return false;
        float pix = pool[i*3], piy = pool[i*3+1];
        float pjx = pool[j*3], pjy = pool[j*3+1];
        float mx = (pix + pjx) * 0.5f, my = (piy + pjy) * 0.5f;
        float dx = pix - pjx, dy = piy - pjy;
        float r2 = (dx*dx + dy*dy) * 0.25f;
        bool g = true;
        #pragma unroll
        for (int k=0;k<N;k++) {
            float ex = pool[k*3] - mx, ey = pool[k*3+1] - my;
            bool ok = (k == i) || (k == j) || (ex*ex + ey*ey > r2);
            g = g && ok;
        }
        return g;
    };
    unsigned long long gb0 = __ballot(gab(i0, j0));
    unsigned long long gb1 = __ballot(gab(i1, j1));
    unsigned long long gb2 = __ballot((t < 16) && gab(i2, j2));
    auto gbit = [&](int p)->int {
        unsigned long long m = (p < 64) ? gb0 : ((p < 128) ? gb1 : gb2);
        return (int)((m >> (p & 63)) & 1ull);
    };
    const int adjA = gbit(p0) | gbit(j0*N+i0) | (i0 == j0);
    const int adjB = gbit(p1) | gbit(j1*N+i1) | (i1 == j1);
    const int adjC = gbit(p2) | gbit(j2*N+i2) | (i2 == j2);

    // ---- GATv2 core: score -> softmax -> aggregate (h-loop kept ROLLED) ----
    auto gat_core = [&](const float* __restrict__ att, const float* __restrict__ gb,
                        float* __restrict__ xout, int rotOut, int useSkip) {
        __syncthreads();   // staged xl/xr visible
        {
            v4f aA = z4, aB = z4, aC = z4;
            for (int h=0; h<HID; h+=4) {
                v4f a4 = *reinterpret_cast<const v4f*>(&att[h]);   // uniform -> scalar load
                {
                    v4f xl = *reinterpret_cast<const v4f*>(&bufL[j0*HID + ((h + 4*j0)&63)]);
                    v4f xr = *reinterpret_cast<const v4f*>(&bufR[i0*HID + ((h + 4*i0)&63)]);
                    v4f s = xl + xr;
                    v4f l = __builtin_elementwise_fma(s4, __builtin_elementwise_min(s, z4),
                                                     __builtin_elementwise_max(s, z4));
                    aA = __builtin_elementwise_fma(a4, l, aA);
                }
                {
                    v4f xl = *reinterpret_cast<const v4f*>(&bufL[j1*HID + ((h + 4*j1)&63)]);
                    v4f xr = *reinterpret_cast<const v4f*>(&bufR[i1*HID + ((h + 4*i1)&63)]);
                    v4f s = xl + xr;
                    v4f l = __builtin_elementwise_fma(s4, __builtin_elementwise_min(s, z4),
                                                     __builtin_elementwise_max(s, z4));
                    aB = __builtin_elementwise_fma(a4, l, aB);
                }
                {
                    v4f xl = *reinterpret_cast<const v4f*>(&bufL[j2*HID + ((h + 4*j2)&63)]);
                    v4f xr = *reinterpret_cast<const v4f*>(&bufR[i2*HID + ((h + 4*i2)&63)]);
                    v4f s = xl + xr;
                    v4f l = __builtin_elementwise_fma(s4, __builtin_elementwise_min(s, z4),
                                                     __builtin_elementwise_max(s, z4));
                    aC = __builtin_elementwise_fma(a4, l, aC);
                }
            }
            float e0 = (aA.x + aA.y) + (aA.z + aA.w);
            float e1 = (aB.x + aB.y) + (aB.z + aB.w);
            float e2 = (aC.x + aC.y) + (aC.z + aC.w);
            pool[p0] = adjA ? e0 : -1e9f;
            pool[p1] = adjB ? e1 : -1e9f;
            if (t < 16) pool[p2] = adjC ? e2 : -1e9f;
        }
        __syncthreads();
        if (t < N) {   // row softmax
            float m = -2e9f;
            #pragma unroll
            for (int j=0;j<N;j++) m = fmaxf(m, pool[t*N+j]);
            float tmp[N]; float sum = 0.f;
            #pragma unroll
            for (int j=0;j<N;j++) { float v = __expf(pool[t*N+j] - m); tmp[j] = v; sum += v; }
            float inv = 1.0f / sum;
            #pragma unroll
            for (int j=0;j<N;j++) pool[t*N+j] = tmp[j] * inv;
        }
        __syncthreads();
        {
            float xj[N];
            #pragma unroll
            for (int j=0;j<N;j++) xj[j] = bufL[j*HID + ((t + 4*j)&63)];
            v4f X0 = {xj[0], xj[1], xj[2],  xj[3]};
            v4f X1 = {xj[4], xj[5], xj[6],  xj[7]};
            v4f X2 = {xj[8], xj[9], xj[10], xj[11]};
            float bias = gb[t];
            #pragma unroll
            for (int i=0;i<N;i++) {
                const v4f* ep = reinterpret_cast<const v4f*>(&pool[i*N]);
                v4f acc = __builtin_elementwise_fma(ep[0], X0,
                          __builtin_elementwise_fma(ep[1], X1, ep[2]*X2));
                float r = bias + ((acc.x + acc.y) + (acc.z + acc.w));
                if (useSkip) r = fmaf(ALPHA, skipv[i], r);
                xout[i*HID + ((t + rotOut*i)&63)] = fmaxf(r, 0.f);
            }
        }
        __syncthreads();
    };

    // ---- stage xl/xr (packed fp32; K-loop kept ROLLED) ----
    auto stage = [&](const float* __restrict__ xin, int rotIn,
                     const float* __restrict__ wlT, const float* __restrict__ wrT,
                     const float* __restrict__ wl, const float* __restrict__ wr) {
        v2f al[N], ar[N];
        #pragma unroll
        for (int i=0;i<N;i++) { al[i] = z2; ar[i] = z2; }
        for (int c=0;c<HID;c+=4) {
            v2f wl01, wl23, wr01, wr23;
            if (TW) {
                v4f w4 = *reinterpret_cast<const v4f*>(&wlT[c]);
                v4f u4 = *reinterpret_cast<const v4f*>(&wrT[c]);
                wl01 = w4.xy; wl23 = w4.zw;
                wr01 = u4.xy; wr23 = u4.zw;
            } else {
                wl01 = (v2f){wl[(c+0)*HID+t], wl[(c+1)*HID+t]};
                wl23 = (v2f){wl[(c+2)*HID+t], wl[(c+3)*HID+t]};
                wr01 = (v2f){wr[(c+0)*HID+t], wr[(c+1)*HID+t]};
                wr23 = (v2f){wr[(c+2)*HID+t], wr[(c+3)*HID+t]};
            }
            #pragma unroll
            for (int i=0;i<N;i++) {
                v4f xv = *reinterpret_cast<const v4f*>(&xin[i*HID + ((c + rotIn*i)&63)]);
                al[i] = __builtin_elementwise_fma(xv.xy, wl01, al[i]);
                al[i] = __builtin_elementwise_fma(xv.zw, wl23, al[i]);
                ar[i] = __builtin_elementwise_fma(xv.xy, wr01, ar[i]);
                ar[i] = __builtin_elementwise_fma(xv.zw, wr23, ar[i]);
            }
        }
        #pragma unroll
        for (int i=0;i<N;i++) {
            bufL[i*HID + ((t + 4*i)&63)] = al[i].x + al[i].y;
            bufR[i*HID + ((t + 4*i)&63)] = ar[i].x + ar[i].y;
        }
    };

    // ---- GAT layer 1 (cin = 1; x0 = lat[:,2] from pool) ----
    {
        float wlv = g1_wl[t], wrv = g1_wr[t];
        #pragma unroll
        for (int i=0;i<N;i++) {
            float v = pool[i*3+2];
            bufL[i*HID + ((t + 4*i)&63)] = v * wlv;
            bufR[i*HID + ((t + 4*i)&63)] = v * wrv;
        }
    }
    gat_core(g1_att, g1_b, bufR, 4, 0);     // x1 -> bufR (rotated)

    // ---- GAT layer 2 ----
    stage(bufR, 4, TW ? wsT + 1*4096 + t*HID : nullptr,
                   TW ? wsT + 2*4096 + t*HID : nullptr, g2_wl, g2_wr);
    gat_core(g2_att, g2_b, xB, 0, 0);       // x2 -> xB (plain; persists)

    // ---- GAT layer 3 ----
    stage(xB, 0, TW ? wsT + 3*4096 + t*HID : nullptr,
                 TW ? wsT + 4*4096 + t*HID : nullptr, g3_wl, g3_wr);
    gat_core(g3_att, g3_b, bufR, 4, 1);     // x3 -> bufR

    // ---- logits head: x3 @ lab_w + lab_b ----
    if (t < N*4) {
        int i = t >> 2, c = t & 3;
        float acc = lab_b[c];
        if (TW) {
            const float* lwT = wsT + 7*4096 + c*HID;
            for (int h=0;h<HID;h+=4) {
                v4f xv = *reinterpret_cast<const v4f*>(&bufR[i*HID + ((h + 4*i)&63)]);
                v4f w4 = *reinterpret_cast<const v4f*>(&lwT[h]);
                acc = fmaf(xv.x, w4.x, acc);
                acc = fmaf(xv.y, w4.y, acc);
                acc = fmaf(xv.z, w4.z, acc);
                acc = fmaf(xv.w, w4.w, acc);
            }
        } else {
            for (int h=0;h<HID;h+=4) {
                v4f xv = *reinterpret_cast<const v4f*>(&bufR[i*HID + ((h + 4*i)&63)]);
                acc = fmaf(xv.x, lab_w[(h+0)*4+c], acc);
                acc = fmaf(xv.y, lab_w[(h+1)*4+c], acc);
                acc = fmaf(xv.z, lab_w[(h+2)*4+c], acc);
                acc = fmaf(xv.w, lab_w[(h+3)*4+c], acc);
            }
        }
        out[OUT2 + (size_t)b*(N*4) + t] = acc;
    }

    // ---- GAT layer 4 ----
    stage(xB, 0, TW ? wsT + 5*4096 + t*HID : nullptr,
                 TW ? wsT + 6*4096 + t*HID : nullptr, g4_wl, g4_wr);
    gat_core(g4_att, g4_b, bufR, 4, 1);     // x4 -> bufR

    // ---- values head ----
    if (t < N) {
        float acc = val_b[0];
        for (int h=0;h<HID;h+=4) {
            v4f xv = *reinterpret_cast<const v4f*>(&bufR[t*HID + ((h + 4*t)&63)]);
            v4f w4 = *reinterpret_cast<const v4f*>(&val_w[h]);
            acc = fmaf(xv.x, w4.x, acc);
            acc = fmaf(xv.y, w4.y, acc);
            acc = fmaf(xv.z, w4.z, acc);
            acc = fmaf(xv.w, w4.w, acc);
        }
        out[OUT3 + (size_t)b*N + t] = acc;
    }
}

extern "C" void kernel_launch(void* const* d_in, const int* in_sizes, int n_in,
                              void* d_out, int out_size, void* d_ws, size_t ws_size,
                              hipStream_t stream) {
    (void)in_sizes; (void)n_in; (void)out_size;
    const bool useT = (ws_size >= (7*4096 + 256)*sizeof(float));
    if (useT) {
        prep_kernel<<<dim3(449), dim3(64), 0, stream>>>(
            (const float*)d_in[3],
            (const float*)d_in[11], (const float*)d_in[12],
            (const float*)d_in[15], (const float*)d_in[16],
            (const float*)d_in[19], (const float*)d_in[20],
            (const float*)d_in[23],
            (float*)d_ws);
        gae_kernel<true><<<dim3(4096), dim3(64), 0, stream>>>(
            (const float*)d_in[0],
            (const float*)d_in[1],  (const float*)d_in[2],
            (const float*)d_in[3],  (const float*)d_in[4],
            (const float*)d_in[5],  (const float*)d_in[6],
            (const float*)d_in[7],  (const float*)d_in[8],  (const float*)d_in[9],  (const float*)d_in[10],
            (const float*)d_in[11], (const float*)d_in[12], (const float*)d_in[13], (const float*)d_in[14],
            (const float*)d_in[15], (const float*)d_in[16], (const float*)d_in[17], (const float*)d_in[18],
            (const float*)d_in[19], (const float*)d_in[20], (const float*)d_in[21], (const float*)d_in[22],
            (const float*)d_in[23], (const float*)d_in[24],
            (const float*)d_in[25], (const float*)d_in[26],
            (const float*)d_in[27], (const float*)d_in[28],
            (const float*)d_ws,
            (float*)d_out);
    } else {
        gae_kernel<false><<<dim3(4096), dim3(64), 0, stream>>>(
            (const float*)d_in[0],
            (const float*)d_in[1],  (const float*)d_in[2],
            (const float*)d_in[3],  (const float*)d_in[4],
            (const float*)d_in[5],  (const float*)d_in[6],
            (const float*)d_in[7],  (const float*)d_in[8],  (const float*)d_in[9],  (const float*)d_in[10],
            (const float*)d_in[11], (const float*)d_in[12], (const float*)d_in[13], (const float*)d_in[14],
            (const float*)d_in[15], (const float*)d_in[16], (const float*)d_in[17], (const float*)d_in[18],
            (const float*)d_in[19], (const float*)d_in[20], (const float*)d_in[21], (const float*)d_in[22],
            (const float*)d_in[23], (const float*)d_in[24],
            (const float*)d_in[25], (const float*)d_in[26],
            (const float*)d_in[27], (const float*)d_in[28],
            nullptr,
            (float*)d_out);
    }
}

// Round 6
// 214.886 us; speedup vs baseline: 1.4031x; 1.0408x over previous
//
#include <hip/hip_runtime.h>
#include <math.h>

#define N     12
#define HID   64
#define STP   68     // padded row stride for bufL/bufR: 272 B rows, 16B-aligned;
                     // row j starts at 16B-chunk 17j -> chunk j%8 -> <=2-way conflicts (free)
#define SLOPE 0.2f
#define ALPHA 0.1f

typedef float v2f __attribute__((ext_vector_type(2)));
typedef float v4f __attribute__((ext_vector_type(4)));

// flat output offsets (float32 elements)
#define OUT0 0          // batch[:,:,:4]
#define OUT1 196608     // batch[:,:,4:5]
#define OUT2 245760     // logits
#define OUT3 442368     // values
#define OUT4 491520     // latent

// ws layout: 7 transposed 64x64 matrices (wsT[m*4096 + t*64 + c] = W[c*64+t]),
// then labT[c*64+h] = lab_w[h*4+c] (256 floats)
__global__ void prep_kernel(const float* __restrict__ enc_w2,
                            const float* __restrict__ g2_wl, const float* __restrict__ g2_wr,
                            const float* __restrict__ g3_wl, const float* __restrict__ g3_wr,
                            const float* __restrict__ g4_wl, const float* __restrict__ g4_wr,
                            const float* __restrict__ lab_w,
                            float* __restrict__ ws) {
    int t = threadIdx.x;
    if (blockIdx.x == 448) {
        #pragma unroll
        for (int c = 0; c < 4; c++) ws[7*4096 + c*64 + t] = lab_w[t*4 + c];
        return;
    }
    int m = blockIdx.x >> 6, c = blockIdx.x & 63;
    const float* src;
    switch (m) {
        case 0: src = enc_w2; break;
        case 1: src = g2_wl;  break;
        case 2: src = g2_wr;  break;
        case 3: src = g3_wl;  break;
        case 4: src = g3_wr;  break;
        case 5: src = g4_wl;  break;
        default: src = g4_wr; break;
    }
    ws[m*4096 + t*64 + c] = src[c*64 + t];
}

// LDS: bufL(12x68) + bufR(12x68) + xB(12x64) + pool(144) = 2544 floats = 10176 B
//   -> 16 blocks/CU (one full residency round at grid 4096).
// Lessons encoded here:
//   R3/R4: do NOT fully unroll the 16-iter K-loops -> accumulator spill (~100 MB
//          scratch traffic). Keep them rolled.
//   R5:    rotate-swizzle addressing costs ~3 VALU per LDS access in rolled
//          loops; padded stride folds row offsets into ds_read immediates.
template<bool TW>
__global__ __launch_bounds__(64, 3) void gae_kernel(
    const float* __restrict__ batch,
    const float* __restrict__ enc_w1, const float* __restrict__ enc_b1,
    const float* __restrict__ enc_w2, const float* __restrict__ enc_b2,
    const float* __restrict__ enc_w3, const float* __restrict__ enc_b3,
    const float* __restrict__ g1_wl, const float* __restrict__ g1_wr,
    const float* __restrict__ g1_att, const float* __restrict__ g1_b,
    const float* __restrict__ g2_wl, const float* __restrict__ g2_wr,
    const float* __restrict__ g2_att, const float* __restrict__ g2_b,
    const float* __restrict__ g3_wl, const float* __restrict__ g3_wr,
    const float* __restrict__ g3_att, const float* __restrict__ g3_b,
    const float* __restrict__ g4_wl, const float* __restrict__ g4_wr,
    const float* __restrict__ g4_att, const float* __restrict__ g4_b,
    const float* __restrict__ lab_w, const float* __restrict__ lab_b,
    const float* __restrict__ val_w, const float* __restrict__ val_b,
    const float* __restrict__ skip_w, const float* __restrict__ skip_b,
    const float* __restrict__ wsT,
    float* __restrict__ out)
{
    const int b = blockIdx.x;
    const int t = threadIdx.x;

    __shared__ __align__(16) float lds[2*N*STP + N*HID + 144];
    float* bufL = lds;                    // stride STP
    float* bufR = lds + N*STP;            // stride STP
    float* xB   = lds + 2*N*STP;          // stride HID (broadcast-read only)
    float* pool = lds + 2*N*STP + N*HID;  // batch(60) -> lat(36) -> e(144)

    const v2f z2 = {0.f, 0.f};
    const v4f z4 = {0.f, 0.f, 0.f, 0.f};
    const v4f s4 = {SLOPE, SLOPE, SLOPE, SLOPE};

    // score-pair decomposition (144 pairs over 64 lanes, 3 slots)
    const int p0 = t,        i0 = p0 / N, j0 = p0 - i0*N;
    const int p1 = t + 64,   i1 = p1 / N, j1 = p1 - i1*N;
    const int p2 = (t < 16) ? (t + 128) : 143;
    const int i2 = p2 / N,   j2 = p2 - i2*N;

    // ---- stage batch into pool, emit passthrough outputs 0/1 ----
    if (t < N*5) {
        float v = batch[b*(N*5) + t];
        pool[t] = v;
        int i = t / 5, f = t - i*5;
        if (f < 4) out[OUT0 + (size_t)b*(N*4) + i*4 + f] = v;
        else       out[OUT1 + (size_t)b*N + i] = v;
    }
    __syncthreads();

    // ---- encoder layer 1 ----
    {
        float acc[N];
        float bias = enc_b1[t];
        #pragma unroll
        for (int i=0;i<N;i++) acc[i] = bias;
        #pragma unroll
        for (int f=0; f<5; f++) {
            float w = enc_w1[f*HID + t];
            #pragma unroll
            for (int i=0;i<N;i++) acc[i] = fmaf(pool[i*5+f], w, acc[i]);
        }
        #pragma unroll
        for (int i=0;i<N;i++) bufL[i*STP + t] = fmaxf(acc[i], 0.f);
    }
    __syncthreads();

    // ---- encoder layer 2 (packed fp32; K-loop ROLLED) ----
    {
        v2f acc[N];
        #pragma unroll
        for (int i=0;i<N;i++) acc[i] = z2;
        const float* w2p = TW ? (wsT + 0*4096 + t*HID) : nullptr;
        for (int c=0;c<HID;c+=4) {
            v2f w01, w23;
            if (TW) {
                v4f w4 = *reinterpret_cast<const v4f*>(&w2p[c]);
                w01 = w4.xy; w23 = w4.zw;
            } else {
                w01 = (v2f){enc_w2[(c+0)*HID+t], enc_w2[(c+1)*HID+t]};
                w23 = (v2f){enc_w2[(c+2)*HID+t], enc_w2[(c+3)*HID+t]};
            }
            #pragma unroll
            for (int i=0;i<N;i++) {
                v4f xv = *reinterpret_cast<const v4f*>(&bufL[i*STP + c]);
                acc[i] = __builtin_elementwise_fma(xv.xy, w01, acc[i]);
                acc[i] = __builtin_elementwise_fma(xv.zw, w23, acc[i]);
            }
        }
        float bias = enc_b2[t];
        #pragma unroll
        for (int i=0;i<N;i++) bufR[i*STP + t] = fmaxf(bias + acc[i].x + acc[i].y, 0.f);
    }
    __syncthreads();

    // ---- latent = h2 @ W3 + b3 (lanes 0..35) -> pool[0..35] ----
    if (t < N*3) {
        int i = t / 3, c = t - i*3;
        float acc = enc_b3[c];
        for (int k=0;k<HID;k+=4) {
            v4f xv = *reinterpret_cast<const v4f*>(&bufR[i*STP + k]);
            acc = fmaf(xv.x, enc_w3[(k+0)*3+c], acc);
            acc = fmaf(xv.y, enc_w3[(k+1)*3+c], acc);
            acc = fmaf(xv.z, enc_w3[(k+2)*3+c], acc);
            acc = fmaf(xv.w, enc_w3[(k+3)*3+c], acc);
        }
        pool[t] = acc;
        out[OUT4 + (size_t)b*(N*3) + t] = acc;
    }
    __syncthreads();

    // ---- skip connection -> registers ----
    float skipv[N];
    {
        float w0 = skip_w[t], w1 = skip_w[HID+t], w2 = skip_w[2*HID+t];
        float bias = skip_b[t];
        #pragma unroll
        for (int i=0;i<N;i++) {
            float v = bias;
            v = fmaf(pool[i*3+0], w0, v);
            v = fmaf(pool[i*3+1], w1, v);
            v = fmaf(pool[i*3+2], w2, v);
            skipv[i] = v;
        }
    }

    // ---- Gabriel adjacency via ballots (no LDS matrix) ----
    auto gab = [&](int i, int j)->bool {
        if (i == j) return false;
        float pix = pool[i*3], piy = pool[i*3+1];
        float pjx = pool[j*3], pjy = pool[j*3+1];
        float mx = (pix + pjx) * 0.5f, my = (piy + pjy) * 0.5f;
        float dx = pix - pjx, dy = piy - pjy;
        float r2 = (dx*dx + dy*dy) * 0.25f;
        bool g = true;
        #pragma unroll
        for (int k=0;k<N;k++) {
            float ex = pool[k*3] - mx, ey = pool[k*3+1] - my;
            bool ok = (k == i) || (k == j) || (ex*ex + ey*ey > r2);
            g = g && ok;
        }
        return g;
    };
    unsigned long long gb0 = __ballot(gab(i0, j0));
    unsigned long long gb1 = __ballot(gab(i1, j1));
    unsigned long long gb2 = __ballot((t < 16) && gab(i2, j2));
    auto gbit = [&](int p)->int {
        unsigned long long m = (p < 64) ? gb0 : ((p < 128) ? gb1 : gb2);
        return (int)((m >> (p & 63)) & 1ull);
    };
    const int adjA = gbit(p0) | gbit(j0*N+i0) | (i0 == j0);
    const int adjB = gbit(p1) | gbit(j1*N+i1) | (i1 == j1);
    const int adjC = gbit(p2) | gbit(j2*N+i2) | (i2 == j2);

    // ---- GATv2 core: score -> softmax -> aggregate (h-loop ROLLED) ----
    auto gat_core = [&](const float* __restrict__ att, const float* __restrict__ gb,
                        float* __restrict__ xout, int strideOut, int useSkip) {
        __syncthreads();   // staged xl/xr visible
        {
            // per-lane row bases; inside the loop all offsets are h-induction only
            const float* Lj0 = &bufL[j0*STP];
            const float* Ri0 = &bufR[i0*STP];
            const float* Lj1 = &bufL[j1*STP];
            const float* Ri1 = &bufR[i1*STP];
            const float* Lj2 = &bufL[j2*STP];
            const float* Ri2 = &bufR[i2*STP];
            v4f aA = z4, aB = z4, aC = z4;
            for (int h=0; h<HID; h+=4) {
                v4f a4 = *reinterpret_cast<const v4f*>(&att[h]);   // uniform -> scalar load
                {
                    v4f xl = *reinterpret_cast<const v4f*>(Lj0 + h);
                    v4f xr = *reinterpret_cast<const v4f*>(Ri0 + h);
                    v4f s = xl + xr;
                    v4f l = __builtin_elementwise_fma(s4, __builtin_elementwise_min(s, z4),
                                                     __builtin_elementwise_max(s, z4));
                    aA = __builtin_elementwise_fma(a4, l, aA);
                }
                {
                    v4f xl = *reinterpret_cast<const v4f*>(Lj1 + h);
                    v4f xr = *reinterpret_cast<const v4f*>(Ri1 + h);
                    v4f s = xl + xr;
                    v4f l = __builtin_elementwise_fma(s4, __builtin_elementwise_min(s, z4),
                                                     __builtin_elementwise_max(s, z4));
                    aB = __builtin_elementwise_fma(a4, l, aB);
                }
                {
                    v4f xl = *reinterpret_cast<const v4f*>(Lj2 + h);
                    v4f xr = *reinterpret_cast<const v4f*>(Ri2 + h);
                    v4f s = xl + xr;
                    v4f l = __builtin_elementwise_fma(s4, __builtin_elementwise_min(s, z4),
                                                     __builtin_elementwise_max(s, z4));
                    aC = __builtin_elementwise_fma(a4, l, aC);
                }
            }
            float e0 = (aA.x + aA.y) + (aA.z + aA.w);
            float e1 = (aB.x + aB.y) + (aB.z + aB.w);
            float e2 = (aC.x + aC.y) + (aC.z + aC.w);
            pool[p0] = adjA ? e0 : -1e9f;
            pool[p1] = adjB ? e1 : -1e9f;
            if (t < 16) pool[p2] = adjC ? e2 : -1e9f;
        }
        __syncthreads();
        if (t < N) {   // row softmax
            float m = -2e9f;
            #pragma unroll
            for (int j=0;j<N;j++) m = fmaxf(m, pool[t*N+j]);
            float tmp[N]; float sum = 0.f;
            #pragma unroll
            for (int j=0;j<N;j++) { float v = __expf(pool[t*N+j] - m); tmp[j] = v; sum += v; }
            float inv = 1.0f / sum;
            #pragma unroll
            for (int j=0;j<N;j++) pool[t*N+j] = tmp[j] * inv;
        }
        __syncthreads();
        {
            float xj[N];
            #pragma unroll
            for (int j=0;j<N;j++) xj[j] = bufL[j*STP + t];   // base t, imm 272j
            v4f X0 = {xj[0], xj[1], xj[2],  xj[3]};
            v4f X1 = {xj[4], xj[5], xj[6],  xj[7]};
            v4f X2 = {xj[8], xj[9], xj[10], xj[11]};
            float bias = gb[t];
            #pragma unroll
            for (int i=0;i<N;i++) {
                const v4f* ep = reinterpret_cast<const v4f*>(&pool[i*N]);
                v4f acc = __builtin_elementwise_fma(ep[0], X0,
                          __builtin_elementwise_fma(ep[1], X1, ep[2]*X2));
                float r = bias + ((acc.x + acc.y) + (acc.z + acc.w));
                if (useSkip) r = fmaf(ALPHA, skipv[i], r);
                xout[i*strideOut + t] = fmaxf(r, 0.f);
            }
        }
        __syncthreads();
    };

    // ---- stage xl/xr (packed fp32; K-loop ROLLED; xin reads are broadcast) ----
    auto stage = [&](const float* __restrict__ xin, int strideIn,
                     const float* __restrict__ wlT, const float* __restrict__ wrT,
                     const float* __restrict__ wl, const float* __restrict__ wr) {
        v2f al[N], ar[N];
        #pragma unroll
        for (int i=0;i<N;i++) { al[i] = z2; ar[i] = z2; }
        for (int c=0;c<HID;c+=4) {
            v2f wl01, wl23, wr01, wr23;
            if (TW) {
                v4f w4 = *reinterpret_cast<const v4f*>(&wlT[c]);
                v4f u4 = *reinterpret_cast<const v4f*>(&wrT[c]);
                wl01 = w4.xy; wl23 = w4.zw;
                wr01 = u4.xy; wr23 = u4.zw;
            } else {
                wl01 = (v2f){wl[(c+0)*HID+t], wl[(c+1)*HID+t]};
                wl23 = (v2f){wl[(c+2)*HID+t], wl[(c+3)*HID+t]};
                wr01 = (v2f){wr[(c+0)*HID+t], wr[(c+1)*HID+t]};
                wr23 = (v2f){wr[(c+2)*HID+t], wr[(c+3)*HID+t]};
            }
            #pragma unroll
            for (int i=0;i<N;i++) {
                v4f xv = *reinterpret_cast<const v4f*>(&xin[i*strideIn + c]);
                al[i] = __builtin_elementwise_fma(xv.xy, wl01, al[i]);
                al[i] = __builtin_elementwise_fma(xv.zw, wl23, al[i]);
                ar[i] = __builtin_elementwise_fma(xv.xy, wr01, ar[i]);
                ar[i] = __builtin_elementwise_fma(xv.zw, wr23, ar[i]);
            }
        }
        #pragma unroll
        for (int i=0;i<N;i++) {
            bufL[i*STP + t] = al[i].x + al[i].y;
            bufR[i*STP + t] = ar[i].x + ar[i].y;
        }
    };

    // ---- GAT layer 1 (cin = 1; x0 = lat[:,2] from pool) ----
    {
        float wlv = g1_wl[t], wrv = g1_wr[t];
        #pragma unroll
        for (int i=0;i<N;i++) {
            float v = pool[i*3+2];
            bufL[i*STP + t] = v * wlv;
            bufR[i*STP + t] = v * wrv;
        }
    }
    gat_core(g1_att, g1_b, bufR, STP, 0);   // x1 -> bufR

    // ---- GAT layer 2 ----
    stage(bufR, STP, TW ? wsT + 1*4096 + t*HID : nullptr,
                     TW ? wsT + 2*4096 + t*HID : nullptr, g2_wl, g2_wr);
    gat_core(g2_att, g2_b, xB, HID, 0);     // x2 -> xB (persists; broadcast-read only)

    // ---- GAT layer 3 ----
    stage(xB, HID, TW ? wsT + 3*4096 + t*HID : nullptr,
                   TW ? wsT + 4*4096 + t*HID : nullptr, g3_wl, g3_wr);
    gat_core(g3_att, g3_b, bufR, STP, 1);   // x3 -> bufR

    // ---- logits head: x3 @ lab_w + lab_b ----
    if (t < N*4) {
        int i = t >> 2, c = t & 3;
        float acc = lab_b[c];
        if (TW) {
            const float* lwT = wsT + 7*4096 + c*HID;
            for (int h=0;h<HID;h+=4) {
                v4f xv = *reinterpret_cast<const v4f*>(&bufR[i*STP + h]);
                v4f w4 = *reinterpret_cast<const v4f*>(&lwT[h]);
                acc = fmaf(xv.x, w4.x, acc);
                acc = fmaf(xv.y, w4.y, acc);
                acc = fmaf(xv.z, w4.z, acc);
                acc = fmaf(xv.w, w4.w, acc);
            }
        } else {
            for (int h=0;h<HID;h+=4) {
                v4f xv = *reinterpret_cast<const v4f*>(&bufR[i*STP + h]);
                acc = fmaf(xv.x, lab_w[(h+0)*4+c], acc);
                acc = fmaf(xv.y, lab_w[(h+1)*4+c], acc);
                acc = fmaf(xv.z, lab_w[(h+2)*4+c], acc);
                acc = fmaf(xv.w, lab_w[(h+3)*4+c], acc);
            }
        }
        out[OUT2 + (size_t)b*(N*4) + t] = acc;
    }

    // ---- GAT layer 4 ----
    stage(xB, HID, TW ? wsT + 5*4096 + t*HID : nullptr,
                   TW ? wsT + 6*4096 + t*HID : nullptr, g4_wl, g4_wr);
    gat_core(g4_att, g4_b, bufR, STP, 1);   // x4 -> bufR

    // ---- values head ----
    if (t < N) {
        float acc = val_b[0];
        for (int h=0;h<HID;h+=4) {
            v4f xv = *reinterpret_cast<const v4f*>(&bufR[t*STP + h]);
            v4f w4 = *reinterpret_cast<const v4f*>(&val_w[h]);
            acc = fmaf(xv.x, w4.x, acc);
            acc = fmaf(xv.y, w4.y, acc);
            acc = fmaf(xv.z, w4.z, acc);
            acc = fmaf(xv.w, w4.w, acc);
        }
        out[OUT3 + (size_t)b*N + t] = acc;
    }
}

extern "C" void kernel_launch(void* const* d_in, const int* in_sizes, int n_in,
                              void* d_out, int out_size, void* d_ws, size_t ws_size,
                              hipStream_t stream) {
    (void)in_sizes; (void)n_in; (void)out_size;
    const bool useT = (ws_size >= (7*4096 + 256)*sizeof(float));
    if (useT) {
        prep_kernel<<<dim3(449), dim3(64), 0, stream>>>(
            (const float*)d_in[3],
            (const float*)d_in[11], (const float*)d_in[12],
            (const float*)d_in[15], (const float*)d_in[16],
            (const float*)d_in[19], (const float*)d_in[20],
            (const float*)d_in[23],
            (float*)d_ws);
        gae_kernel<true><<<dim3(4096), dim3(64), 0, stream>>>(
            (const float*)d_in[0],
            (const float*)d_in[1],  (const float*)d_in[2],
            (const float*)d_in[3],  (const float*)d_in[4],
            (const float*)d_in[5],  (const float*)d_in[6],
            (const float*)d_in[7],  (const float*)d_in[8],  (const float*)d_in[9],  (const float*)d_in[10],
            (const float*)d_in[11], (const float*)d_in[12], (const float*)d_in[13], (const float*)d_in[14],
            (const float*)d_in[15], (const float*)d_in[16], (const float*)d_in[17], (const float*)d_in[18],
            (const float*)d_in[19], (const float*)d_in[20], (const float*)d_in[21], (const float*)d_in[22],
            (const float*)d_in[23], (const float*)d_in[24],
            (const float*)d_in[25], (const float*)d_in[26],
            (const float*)d_in[27], (const float*)d_in[28],
            (const float*)d_ws,
            (float*)d_out);
    } else {
        gae_kernel<false><<<dim3(4096), dim3(64), 0, stream>>>(
            (const float*)d_in[0],
            (const float*)d_in[1],  (const float*)d_in[2],
            (const float*)d_in[3],  (const float*)d_in[4],
            (const float*)d_in[5],  (const float*)d_in[6],
            (const float*)d_in[7],  (const float*)d_in[8],  (const float*)d_in[9],  (const float*)d_in[10],
            (const float*)d_in[11], (const float*)d_in[12], (const float*)d_in[13], (const float*)d_in[14],
            (const float*)d_in[15], (const float*)d_in[16], (const float*)d_in[17], (const float*)d_in[18],
            (const float*)d_in[19], (const float*)d_in[20], (const float*)d_in[21], (const float*)d_in[22],
            (const float*)d_in[23], (const float*)d_in[24],
            (const float*)d_in[25], (const float*)d_in[26],
            (const float*)d_in[27], (const float*)d_in[28],
            nullptr,
            (float*)d_out);
    }
}